// Round 4
// baseline (280.525 us; speedup 1.0000x reference)
//
#include <hip/hip_runtime.h>
#include <stdint.h>

// ModulatedConv2d: B=8, C=512, O=512, K=3, WDIM=512, H=W=64
// Round-9: k_conv BK 64->32. Per-iter LDS 33KB -> 4 blocks/CU (16 waves/CU),
//   doubling the independent stage/compute streams per SIMD so barrier drains
//   of one block hide under MFMA of three others. Same proven sync structure
//   (stage -> sync -> MFMA -> sync), 48 iterations of 48 MFMA/wave.
//   4-chunk XOR swizzle with (row>>1) rotation (conflict-free b128, verified).
//   s_setprio(1) around MFMA cluster (T5, independent-block regime).

#define MOD_SCALE  0.044194173824159216f   // 1/sqrt(512)
#define CONV_SCALE 0.014731391274719739f   // 1/sqrt(4608)

typedef __attribute__((ext_vector_type(4))) float f32x4;
typedef __attribute__((ext_vector_type(8))) short bf16x8;

__device__ inline unsigned short f2bf(float f) {   // round-to-nearest-even
  uint32_t u = __float_as_uint(f);
  uint32_t r = (u + 0x7fffu + ((u >> 16) & 1u)) >> 16;
  return (unsigned short)r;
}

__device__ inline void gload_lds16(const void* g, void* l) {
  __builtin_amdgcn_global_load_lds(
      (const __attribute__((address_space(1))) void*)g,
      (__attribute__((address_space(3))) void*)l, 16, 0, 0);
}

// ---------- style: s[b][c] = w[b].modw[c]*MOD_SCALE + modb[c] + 1 ----------
__global__ __launch_bounds__(256) void k_style(const float* __restrict__ w,
                                               const float* __restrict__ modw,
                                               const float* __restrict__ modb,
                                               float* __restrict__ s_out) {
  __shared__ float red[256];
  const int tid = threadIdx.x;
  const int sb = blockIdx.x;
  const int cb = sb & 7, b = sb >> 3;
  const int cl = tid >> 2, qq = tid & 3;
  const int c = (cb << 6) + cl;
  const float4* wd = (const float4*)(w + (b << 9) + (qq << 7));
  const float4* md = (const float4*)(modw + ((size_t)c << 9) + (qq << 7));
  float acc = 0.f;
#pragma unroll
  for (int i = 0; i < 32; ++i) {
    float4 a = wd[i], m = md[i];
    acc += a.x * m.x + a.y * m.y + a.z * m.z + a.w * m.w;
  }
  red[tid] = acc;
  __syncthreads();
  if (tid < 64) {
    float v = red[tid * 4] + red[tid * 4 + 1] + red[tid * 4 + 2] + red[tid * 4 + 3];
    int cc = (cb << 6) + tid;
    s_out[(b << 9) + cc] = v * MOD_SCALE + modb[cc] + 1.0f;
  }
}

// ---------- prep: xpad[b][py][px][c] = bf16(x[b][c][py-1][px-1] * s[b][c]) ----------
__global__ __launch_bounds__(256) void k_prep(const float* __restrict__ x,
                                              const float* __restrict__ s,
                                              unsigned short* __restrict__ xp) {
  __shared__ uint32_t tb[64 * 260];   // 66,560 B
  const int blk = blockIdx.x;
  const int tid = threadIdx.x;
  if (blk < 512) {
    const int b = blk >> 6, y = blk & 63;
    const int px4 = tid & 15;          // which float4 of the 64-px row
    const int cp  = tid >> 4;          // 0..15
    const float* xb = x + (size_t)(b << 9) * 4096 + (y << 6) + (px4 << 2);
    const float* sb = s + (b << 9);
#pragma unroll
    for (int it = 0; it < 16; ++it) {
      const int cpair = cp + (it << 4);        // 0..255
      const int c0 = cpair << 1;
      const float4 a0 = *(const float4*)(xb + (size_t)c0 * 4096);
      const float4 a1 = *(const float4*)(xb + (size_t)(c0 + 1) * 4096);
      const float s0 = sb[c0], s1 = sb[c0 + 1];
      const int pxb = px4 << 2;
      tb[(pxb + 0) * 260 + cpair] = (uint32_t)f2bf(a0.x * s0) | ((uint32_t)f2bf(a1.x * s1) << 16);
      tb[(pxb + 1) * 260 + cpair] = (uint32_t)f2bf(a0.y * s0) | ((uint32_t)f2bf(a1.y * s1) << 16);
      tb[(pxb + 2) * 260 + cpair] = (uint32_t)f2bf(a0.z * s0) | ((uint32_t)f2bf(a1.z * s1) << 16);
      tb[(pxb + 3) * 260 + cpair] = (uint32_t)f2bf(a0.w * s0) | ((uint32_t)f2bf(a1.w * s1) << 16);
    }
    __syncthreads();
    const int wv = tid >> 6, l = tid & 63;
    uint32_t* xpw = (uint32_t*)xp;
#pragma unroll
    for (int it = 0; it < 16; ++it) {
      const int px = (wv << 4) + it;
      const uint4 v = *(const uint4*)(tb + px * 260 + (l << 2));  // 16B-aligned
      const size_t base = ((size_t)b * 4356 + (size_t)(y + 1) * 66 + (px + 1)) << 8;
      ((uint4*)(xpw + base))[l] = v;   // wave writes contiguous 1 KB
    }
  } else {
    // ---- zero pad border (260 segments x 8 batches) ----
    const int q = blk - 512;
    const int b = q / 260, p = q - b * 260;
    int py, px;
    if (p < 66)       { py = 0;       px = p; }
    else if (p < 132) { py = 65;      px = p - 66; }
    else if (p < 196) { py = p - 131; px = 0; }
    else              { py = p - 195; px = 65; }
    uint32_t* dst = (uint32_t*)(xp + ((size_t)b * 4356 + py * 66 + px) * 512);
    dst[tid] = 0u;
  }
}

// ---------- fused demod + weight convert: one block per o ----------
__global__ __launch_bounds__(256) void k_fwd(const float* __restrict__ bw,
                                             const float* __restrict__ s,
                                             unsigned short* __restrict__ awT,
                                             float* __restrict__ d_out) {
  __shared__ float lw[4608];   // bw row, [c][tap]
  __shared__ float ls[4096];   // s, [b][c]
  __shared__ float red[32];
  const int tid = threadIdx.x;
  const int o = blockIdx.x;
  {
    const float4* src = (const float4*)(bw + (size_t)o * 4608);
    float4* dst = (float4*)lw;
#pragma unroll
    for (int i = 0; i < 4; ++i) dst[tid + (i << 8)] = src[tid + (i << 8)];
    if (tid < 128) dst[tid + 1024] = src[tid + 1024];
  }
  {
    const float4* src = (const float4*)s;
    float4* dst = (float4*)ls;
#pragma unroll
    for (int i = 0; i < 4; ++i) dst[tid + (i << 8)] = src[tid + (i << 8)];
  }
  __syncthreads();
  const int c0 = tid << 1;
  const int base = c0 * 9;
  float wq0 = 0.f, wq1 = 0.f;
#pragma unroll
  for (int j = 0; j < 9; ++j) {
    float a = lw[base + j];      wq0 += a * a;
    float b2 = lw[base + 9 + j]; wq1 += b2 * b2;
  }
  const int lane = tid & 63, wv = tid >> 6;
#pragma unroll
  for (int b = 0; b < 8; ++b) {
    float s0 = ls[(b << 9) + c0], s1 = ls[(b << 9) + c0 + 1];
    float v = wq0 * s0 * s0 + wq1 * s1 * s1;
#pragma unroll
    for (int off = 32; off > 0; off >>= 1) v += __shfl_down(v, off, 64);
    if (lane == 0) red[(b << 2) + wv] = v;
  }
  __syncthreads();
  if (tid < 8) {
    float a = red[tid << 2] + red[(tid << 2) + 1] + red[(tid << 2) + 2] + red[(tid << 2) + 3];
    d_out[(tid << 9) + o] = rsqrtf(a * (1.0f / 4608.0f)) * CONV_SCALE;
  }
  // bf16 convert of the raw base weight (once, no per-batch loop)
  uint32_t* dst = (uint32_t*)(awT + (size_t)o * 4608);
#pragma unroll
  for (int j = 0; j < 9; ++j)
    dst[(j << 8) + tid] = (uint32_t)f2bf(lw[base + j]) |
                          ((uint32_t)f2bf(lw[base + 9 + j]) << 16);
}

// ---------- main conv: 128x128 tile, BK=32, 4 blocks/CU ----------
// LDS: As 3 tap-panels 128x32 (24 KB) + Bs 132-px halo strip x 32 (8.25 KB).
// Swizzle: 4 chunks of 8 ushort per 32-k row; phys = (logical + (row>>1)) & 3.
// Staging thread t: row = g*64 + (t>>2), phys chunk t&3,
//   logical chunk sl = ((t&3) - (t>>3)) & 3 (g-independent, verified).
__global__ __launch_bounds__(256, 4) void k_conv(const unsigned short* __restrict__ awT,
                                                 const unsigned short* __restrict__ xpad,
                                                 const float* __restrict__ dmod,
                                                 float* __restrict__ out) {
  __shared__ alignas(16) unsigned short As[3 * 4096];  // 24 KB
  __shared__ alignas(16) unsigned short Bs[4224];      // 8.25 KB
  const int tid = threadIdx.x;
  const int b  = blockIdx.z;
  const int m0 = blockIdx.y << 7;
  const int n0 = blockIdx.x << 7;
  const int y0 = n0 >> 6;

  const int srow4 = tid >> 2;                       // 0..63 (row within pass)
  const int sl    = ((tid & 3) - (tid >> 3)) & 3;   // logical chunk to fetch
  const int scol  = sl << 3;

  const unsigned short* A0 = awT + (size_t)(m0 + srow4) * 4608 + scol;
  const unsigned short* B0 = xpad + (size_t)b * (66 * 66 * 512)
                                  + (size_t)(y0 * 66 + srow4) * 512 + scol;

  const int lane = tid & 63;
  const int wv   = tid >> 6;
  const int moff = (wv >> 1) << 6;
  const int noff = (wv & 1) << 6;
  const int noffp = noff ? 66 : 0;   // halo-strip row base for this wave
  const int lm   = lane & 15;
  const int g4   = lane >> 4;

  // A reader offset (ushort index within a panel); chunk const across i.
  const int arow = moff + lm;
  const int aoff = arow * 32 + (((g4 + (arow >> 1)) & 3) << 3);
  // B reader offsets per kx: row = noffp + lm + kx
  int boff[3];
#pragma unroll
  for (int kx = 0; kx < 3; ++kx) {
    const int rb = noffp + lm + kx;
    boff[kx] = rb * 32 + (((g4 + (rb >> 1)) & 3) << 3);
  }

  f32x4 acc[4][4];
#pragma unroll
  for (int i = 0; i < 4; ++i)
#pragma unroll
    for (int j = 0; j < 4; ++j) acc[i][j] = (f32x4){0.f, 0.f, 0.f, 0.f};

#pragma unroll 1
  for (int ky = 0; ky < 3; ++ky) {
#pragma unroll 1
    for (int kb = 0; kb < 16; ++kb) {
      const int kcol = kb << 5;
      // stage 3 A tap-panels (2 passes each: rows 0..63, 64..127)
#pragma unroll
      for (int kx = 0; kx < 3; ++kx) {
        const unsigned short* Ap = A0 + ((ky * 3 + kx) << 9) + kcol;
#pragma unroll
        for (int g = 0; g < 2; ++g)
          gload_lds16(Ap + (size_t)(g << 6) * 4608,
                      As + (kx << 12) + (((g << 8) + tid) << 3));
      }
      // stage B halo strip: 132 rows x 32 k (2 passes + 4-row remainder)
      const unsigned short* Bp = B0 + (size_t)(ky * 66) * 512 + kcol;
#pragma unroll
      for (int g = 0; g < 2; ++g)
        gload_lds16(Bp + (size_t)(g << 6) * 512, Bs + (((g << 8) + tid) << 3));
      if (tid < 16) gload_lds16(Bp + (size_t)128 * 512, Bs + ((512 + tid) << 3));
      __syncthreads();
      __builtin_amdgcn_s_setprio(1);
#pragma unroll
      for (int kx = 0; kx < 3; ++kx) {
        bf16x8 af[4], bf[4];
        const unsigned short* pa = As + (kx << 12) + aoff;
        const unsigned short* pb = Bs + boff[kx];
#pragma unroll
        for (int i = 0; i < 4; ++i) af[i] = *(const bf16x8*)(pa + (i << 9));
#pragma unroll
        for (int j = 0; j < 4; ++j) bf[j] = *(const bf16x8*)(pb + (j << 9));
#pragma unroll
        for (int i = 0; i < 4; ++i)
#pragma unroll
          for (int j = 0; j < 4; ++j)
            acc[i][j] = __builtin_amdgcn_mfma_f32_16x16x32_bf16(af[i], bf[j], acc[i][j], 0, 0, 0);
      }
      __builtin_amdgcn_s_setprio(0);
      __syncthreads();
    }
  }

  // epilogue: D layout col=lane&15 (pixel), row=(lane>>4)*4+reg (o); apply D[b][o]
  const float* dB = dmod + (b << 9) + m0 + moff;
  float* op = out + (size_t)((b << 9) + m0 + moff) * 4096 + n0 + noff;
#pragma unroll
  for (int i = 0; i < 4; ++i) {
#pragma unroll
    for (int r = 0; r < 4; ++r) {
      const int m = i * 16 + (g4 << 2) + r;
      const float dm = dB[m];
#pragma unroll
      for (int j = 0; j < 4; ++j)
        op[(size_t)m * 4096 + (j << 4) + lm] = acc[i][j][r] * dm;
    }
  }
}

extern "C" void kernel_launch(void* const* d_in, const int* in_sizes, int n_in,
                              void* d_out, int out_size, void* d_ws, size_t ws_size,
                              hipStream_t stream) {
  const float* x    = (const float*)d_in[0];   // (8,512,64,64)
  const float* w    = (const float*)d_in[1];   // (8,512)
  const float* bw   = (const float*)d_in[2];   // (1,512,512,3,3)
  const float* modw = (const float*)d_in[3];   // (512,512)
  const float* modb = (const float*)d_in[4];   // (512,)
  float* out = (float*)d_out;                  // (8,512,64,64) fp32
  char* ws = (char*)d_ws;

  float* s_buf = (float*)(ws);                              // 16 KB
  float* d_buf = (float*)(ws + 16384);                      // 16 KB
  unsigned short* awT  = (unsigned short*)(ws + 32768);     // 4,718,592 B
  unsigned short* xpad = (unsigned short*)(ws + 4751360);   // 35,684,352 B

  (void)in_sizes; (void)n_in; (void)out_size; (void)ws_size;

  k_style<<<64,   256, 0, stream>>>(w, modw, modb, s_buf);
  k_fwd  <<<512,  256, 0, stream>>>(bw, s_buf, awT, d_buf);
  k_prep <<<2592, 256, 0, stream>>>(x, s_buf, xpad);
  k_conv <<<dim3(32, 4, 8), 256, 0, stream>>>(awT, xpad, d_buf, out);
}